// Round 10
// baseline (572.815 us; speedup 1.0000x reference)
//
#include <hip/hip_runtime.h>
#include <hip/hip_fp16.h>
#include <math.h>

#define D1 128
#define NEG 0.2f
#define NODE_SHIFT 9
#define BIN_NODES 512
#define MAXBIN 256

typedef short v8s __attribute__((ext_vector_type(8)));
typedef float v4f __attribute__((ext_vector_type(4)));

__device__ __forceinline__ float lrelu(float v){ return v > 0.f ? v : NEG * v; }
__device__ __forceinline__ float elu_f(float v){ return v > 0.f ? v : __expf(v) - 1.f; }

__device__ __forceinline__ unsigned short bf16s(float f){
    unsigned u = __float_as_uint(f);
    return (unsigned short)((u + 0x7fffu + ((u >> 16) & 1u)) >> 16);   // RNE
}
__device__ __forceinline__ float bf2f(unsigned short s){
    return __uint_as_float(((unsigned)s) << 16);
}
__device__ __forceinline__ unsigned f2h2(float a, float b){           // a->low, b->high
    return ((unsigned)__half_as_ushort(__float2half_rn(b)) << 16) |
           (unsigned)__half_as_ushort(__float2half_rn(a));
}
__device__ __forceinline__ float2 h2f2(unsigned u){
    float lo = __half2float(__ushort_as_half((unsigned short)(u & 0xffffu)));
    float hi = __half2float(__ushort_as_half((unsigned short)(u >> 16)));
    return make_float2(lo, hi);
}
__device__ __forceinline__ void split8(const float* f, v8s& hi, v8s& lo){
    #pragma unroll
    for (int i = 0; i < 8; i++){
        unsigned short h = bf16s(f[i]);
        ((short*)&hi)[i] = (short)h;
        ((short*)&lo)[i] = (short)bf16s(f[i] - bf2f(h));
    }
}

// ---------------- binned CSR build ----------------

__global__ __launch_bounds__(256) void kb_hist(const int* __restrict__ ei,
                                               int* __restrict__ binCnt,
                                               int n_edges, int etot, int nbin){
    __shared__ int h[MAXBIN];
    for (int i = threadIdx.x; i < nbin; i += 256) h[i] = 0;
    __syncthreads();
    int stride = gridDim.x * 256;
    for (int e = blockIdx.x * 256 + threadIdx.x; e < etot; e += stride){
        int dst = (e < n_edges) ? ei[n_edges + e] : (e - n_edges);
        atomicAdd(&h[dst >> NODE_SHIFT], 1);
    }
    __syncthreads();
    for (int i = threadIdx.x; i < nbin; i += 256)
        if (h[i]) atomicAdd(&binCnt[i], h[i]);
}

__global__ void kb_scan(const int* __restrict__ binCnt, int* __restrict__ binStart,
                        int* __restrict__ binCursor, int nbin,
                        int* __restrict__ rowptr, int n_nodes, int etot){
    if (threadIdx.x == 0){
        int run = 0;
        for (int b = 0; b < nbin; b++){
            binStart[b] = run; binCursor[b] = run; run += binCnt[b];
        }
        binStart[nbin] = run;
        rowptr[n_nodes] = etot;
    }
}

__global__ __launch_bounds__(256) void kb_scatter(const int* __restrict__ ei,
                                                  int* __restrict__ binCursor,
                                                  uint2* __restrict__ staged,
                                                  int n_edges, int etot, int nbin){
    __shared__ int cnt[MAXBIN];
    __shared__ int base[MAXBIN];
    int e0 = blockIdx.x * 4096;
    for (int i = threadIdx.x; i < nbin; i += 256) cnt[i] = 0;
    __syncthreads();
    #pragma unroll 4
    for (int r = 0; r < 16; r++){
        int e = e0 + r * 256 + threadIdx.x;
        if (e < etot){
            int dst = (e < n_edges) ? ei[n_edges + e] : (e - n_edges);
            atomicAdd(&cnt[dst >> NODE_SHIFT], 1);
        }
    }
    __syncthreads();
    for (int i = threadIdx.x; i < nbin; i += 256){
        base[i] = cnt[i] ? atomicAdd(&binCursor[i], cnt[i]) : 0;
        cnt[i] = 0;
    }
    __syncthreads();
    #pragma unroll 4
    for (int r = 0; r < 16; r++){
        int e = e0 + r * 256 + threadIdx.x;
        if (e < etot){
            int src, dst;
            if (e < n_edges){ src = ei[e]; dst = ei[n_edges + e]; }
            else            { src = dst = e - n_edges; }
            int b = dst >> NODE_SHIFT;
            int p = base[b] + atomicAdd(&cnt[b], 1);
            staged[p] = make_uint2((unsigned)src, (unsigned)dst);
        }
    }
}

__global__ __launch_bounds__(512) void kb_final(const uint2* __restrict__ staged,
                                                const int* __restrict__ binStart,
                                                int* __restrict__ rowptr,
                                                int* __restrict__ eidx, int n_nodes){
    __shared__ int deg[BIN_NODES];
    __shared__ int cur[BIN_NODES];
    int b = blockIdx.x;
    int nbase = b << NODE_SHIFT;
    int s0 = binStart[b], s1 = binStart[b + 1];
    deg[threadIdx.x] = 0;
    __syncthreads();
    for (int i = s0 + threadIdx.x; i < s1; i += 512)
        atomicAdd(&deg[staged[i].y & (BIN_NODES - 1)], 1);
    __syncthreads();
    int v = deg[threadIdx.x];
    cur[threadIdx.x] = v;
    __syncthreads();
    for (int off = 1; off < BIN_NODES; off <<= 1){
        int t = (threadIdx.x >= off) ? cur[threadIdx.x - off] : 0;
        __syncthreads();
        cur[threadIdx.x] += t;
        __syncthreads();
    }
    int excl = cur[threadIdx.x] - v;           // exclusive prefix within bin
    int node = nbase + threadIdx.x;
    if (node < n_nodes) rowptr[node] = s0 + excl;
    cur[threadIdx.x] = s0 + excl;              // becomes cursor
    __syncthreads();
    for (int i = s0 + threadIdx.x; i < s1; i += 512){
        uint2 pr = staged[i];
        int p = atomicAdd(&cur[pr.y & (BIN_NODES - 1)], 1);
        eidx[p] = (int)pr.x;
    }
}

// ---------------- weight prep: split W into bf16 hi/lo, k-packed B' layout ----

__global__ void k_prepw(const float* __restrict__ W1, const float* __restrict__ W2,
                        const float* __restrict__ W3, unsigned short* __restrict__ Bp){
    int t = blockIdx.x * 256 + threadIdx.x;          // 0..49151
    if (t >= 49152) return;
    int w = t >> 14;
    int r = t & 16383;
    int k = r >> 7, j = r & 127;
    const float* W = (w == 0) ? W1 : (w == 1) ? W2 : W3;
    float val = W[j * 128 + k];
    unsigned short hi = bf16s(val);
    unsigned short lo = bf16s(val - bf2f(hi));
    int idx = (k >> 3) * 1024 + j * 8 + (k & 7);
    Bp[w * 32768 + idx] = hi;
    Bp[w * 32768 + 16384 + idx] = lo;
}

// ---------------- split-bf16 MFMA GEMM + fused attention coefficients --------
// v4: whole-B 64 KB dynamic-LDS single stage (ONE barrier), all A loads hoisted,
// uninterrupted 192-MFMA stream. FP32SRC=1: layer-1 reads fp32 x, splits in regs.

template<int FP32SRC>
__global__ __launch_bounds__(256) void k_mgemm(
        const float* __restrict__ Xf,
        const unsigned short* __restrict__ Xhi, const unsigned short* __restrict__ Xlo,
        const unsigned short* __restrict__ Bp,
        const float* __restrict__ aw_s, const float* __restrict__ aw_d,
        unsigned short* __restrict__ Hh,
        float* __restrict__ asrc, float* __restrict__ adst, int n_rows){
    extern __shared__ unsigned short Bs[];       // 64 KB: hi[16384 sh] + lo[16384 sh]
    int lane = threadIdx.x & 63;
    int li = lane & 15, quad = lane >> 4;
    int wv = threadIdx.x >> 6;
    int r0 = blockIdx.x * 128 + wv * 32;

    int row0 = r0 + li;
    int row1 = r0 + 16 + li;
    int rc0 = row0 < n_rows ? row0 : 0;
    int rc1 = row1 < n_rows ? row1 : 0;

    // hoist A fragment loads / splits
    v8s ah0[4], al0[4], ah1[4], al1[4];
    #pragma unroll
    for (int ks = 0; ks < 4; ks++){
        int koff = ks * 32 + quad * 8;
        if (FP32SRC){
            float f0[8], f1[8];
            *(float4*)&f0[0] = *(const float4*)(Xf + (size_t)rc0 * 128 + koff);
            *(float4*)&f0[4] = *(const float4*)(Xf + (size_t)rc0 * 128 + koff + 4);
            *(float4*)&f1[0] = *(const float4*)(Xf + (size_t)rc1 * 128 + koff);
            *(float4*)&f1[4] = *(const float4*)(Xf + (size_t)rc1 * 128 + koff + 4);
            split8(f0, ah0[ks], al0[ks]);
            split8(f1, ah1[ks], al1[ks]);
        } else {
            ah0[ks] = *(const v8s*)(Xhi + (size_t)rc0 * 128 + koff);
            al0[ks] = *(const v8s*)(Xlo + (size_t)rc0 * 128 + koff);
            ah1[ks] = *(const v8s*)(Xhi + (size_t)rc1 * 128 + koff);
            al1[ks] = *(const v8s*)(Xlo + (size_t)rc1 * 128 + koff);
        }
    }

    // stage whole B (hi+lo contiguous in Bp): 4096 float4
    #pragma unroll
    for (int i = 0; i < 16; i++){
        int idx = threadIdx.x + i * 256;
        ((float4*)Bs)[idx] = ((const float4*)Bp)[idx];
    }
    __syncthreads();

    v4f acc[2][8];
    #pragma unroll
    for (int m = 0; m < 2; m++)
        #pragma unroll
        for (int t = 0; t < 8; t++)
            acc[m][t] = (v4f){0.f, 0.f, 0.f, 0.f};

    #pragma unroll
    for (int ks = 0; ks < 4; ks++){
        #pragma unroll
        for (int t = 0; t < 8; t++){
            int bo = (ks * 4 + quad) * 1024 + (t * 16 + li) * 8;
            v8s bh = *(const v8s*)(Bs + bo);
            v8s bl = *(const v8s*)(Bs + 16384 + bo);
            acc[0][t] = __builtin_amdgcn_mfma_f32_16x16x32_bf16(ah0[ks], bh, acc[0][t], 0, 0, 0);
            acc[0][t] = __builtin_amdgcn_mfma_f32_16x16x32_bf16(ah0[ks], bl, acc[0][t], 0, 0, 0);
            acc[0][t] = __builtin_amdgcn_mfma_f32_16x16x32_bf16(al0[ks], bh, acc[0][t], 0, 0, 0);
            acc[1][t] = __builtin_amdgcn_mfma_f32_16x16x32_bf16(ah1[ks], bh, acc[1][t], 0, 0, 0);
            acc[1][t] = __builtin_amdgcn_mfma_f32_16x16x32_bf16(ah1[ks], bl, acc[1][t], 0, 0, 0);
            acc[1][t] = __builtin_amdgcn_mfma_f32_16x16x32_bf16(al1[ks], bh, acc[1][t], 0, 0, 0);
        }
    }

    // epilogue 1: fp16 mirror
    #pragma unroll
    for (int m = 0; m < 2; m++){
        #pragma unroll
        for (int t = 0; t < 8; t++){
            #pragma unroll
            for (int r = 0; r < 4; r++){
                float v  = acc[m][t][r];
                float vo = __shfl_xor(v, 1);
                if (!(li & 1)){
                    int row = r0 + m * 16 + quad * 4 + r;
                    if (row < n_rows)
                        *(unsigned*)(Hh + (size_t)row * 128 + t * 16 + li) = f2h2(v, vo);
                }
            }
        }
    }

    // epilogue 2: fused attention coefficients
    float as8[8], ad8[8];
    #pragma unroll
    for (int t = 0; t < 8; t++){
        as8[t] = aw_s[t * 16 + li];
        ad8[t] = aw_d[t * 16 + li];
    }
    #pragma unroll
    for (int m = 0; m < 2; m++){
        #pragma unroll
        for (int r = 0; r < 4; r++){
            float sp[4], dp[4];
            #pragma unroll
            for (int h = 0; h < 4; h++){
                sp[h] = acc[m][2*h][r] * as8[2*h] + acc[m][2*h+1][r] * as8[2*h+1];
                dp[h] = acc[m][2*h][r] * ad8[2*h] + acc[m][2*h+1][r] * ad8[2*h+1];
            }
            #pragma unroll
            for (int off = 1; off < 16; off <<= 1){
                #pragma unroll
                for (int h = 0; h < 4; h++){
                    sp[h] += __shfl_xor(sp[h], off);
                    dp[h] += __shfl_xor(dp[h], off);
                }
            }
            if (li == 0){
                int row = r0 + m * 16 + quad * 4 + r;
                if (row < n_rows){
                    ((float4*)asrc)[row] = make_float4(sp[0], sp[1], sp[2], sp[3]);
                    ((float4*)adst)[row] = make_float4(dp[0], dp[1], dp[2], dp[3]);
                }
            }
        }
    }
}

// ---------------- fused softmax + aggregation, one wave per node ----------------
// Single pass, per-lane private denominator. Exp dedup: per 8-edge batch, lanes
// 0..31 each compute ONE (edge,head) weight; head groups fetch all 8 via shfl.

template<int MEAN>
__global__ __launch_bounds__(256) void k_aggr(
        const unsigned* __restrict__ Hh,
        const float* __restrict__ asrc, const float* __restrict__ adst,
        const int* __restrict__ rowptr, const int* __restrict__ eidx,
        const float* __restrict__ bias,
        unsigned short* __restrict__ Oh, unsigned short* __restrict__ Ol,
        float* __restrict__ Of, int n_nodes){
    int lane = threadIdx.x & 63;
    int wid  = threadIdx.x >> 6;
    int n = blockIdx.x * 4 + wid;
    if (n >= n_nodes) return;
    int row0 = rowptr[n];
    int deg  = rowptr[n + 1] - row0;
    const int* ep = eidx + row0;
    unsigned hd = (unsigned)(lane >> 4);          // this lane's head
    unsigned ul = (unsigned)lane;
    float4 ad = ((const float4*)adst)[n];
    float adh = hd == 0 ? ad.x : hd == 1 ? ad.y : hd == 2 ? ad.z : ad.w;
    unsigned wh = (ul >> 3) & 3;                  // w-computation role head
    float adw = wh == 0 ? ad.x : wh == 1 ? ad.y : wh == 2 ? ad.z : ad.w;
    int wsrc = (int)(hd * 8);                     // shfl source base

    float accx = 0.f, accy = 0.f, den = 0.f;
    int i = 0;
    for (; i + 8 <= deg; i += 8){
        unsigned s[8];
        #pragma unroll
        for (int j = 0; j < 8; j++) s[j] = (unsigned)ep[i + j];
        // role lanes (0..31, dup 32..63): w for edge (ul&7), head wh
        float aW = asrc[s[ul & 7] * 4u + wh];
        float w = __expf(lrelu(aW + adw));
        unsigned hw[8];
        #pragma unroll
        for (int j = 0; j < 8; j++) hw[j] = Hh[s[j] * 64u + ul];
        #pragma unroll
        for (int j = 0; j < 8; j++){
            float wj = __shfl(w, wsrc + j);
            float2 hv = h2f2(hw[j]);
            den  += wj;
            accx += wj * hv.x;
            accy += wj * hv.y;
        }
    }
    for (; i < deg; i++){
        unsigned s = (unsigned)ep[i];
        float w = __expf(lrelu(asrc[s * 4u + hd] + adh));
        float2 hv = h2f2(Hh[s * 64u + ul]);
        den  += w;
        accx += w * hv.x;
        accy += w * hv.y;
    }
    float rdh = 1.f / den;
    accx *= rdh; accy *= rdh;

    int c = lane * 2;
    if (!MEAN){
        float ox = elu_f(accx + bias[c]);
        float oy = elu_f(accy + bias[c + 1]);
        unsigned short hx = bf16s(ox), hy = bf16s(oy);
        unsigned short lx = bf16s(ox - bf2f(hx)), ly = bf16s(oy - bf2f(hy));
        *(ushort2*)(Oh + (size_t)n * 128 + c) = make_ushort2(hx, hy);
        *(ushort2*)(Ol + (size_t)n * 128 + c) = make_ushort2(lx, ly);
    } else {
        float sx = accx, sy = accy;
        sx += __shfl_xor(sx, 16); sy += __shfl_xor(sy, 16);
        sx += __shfl_xor(sx, 32); sy += __shfl_xor(sy, 32);
        if (lane < 16){
            int cc = lane * 2;
            float ox = elu_f(sx * 0.25f + bias[cc]);
            float oy = elu_f(sy * 0.25f + bias[cc + 1]);
            *(float2*)(Of + (size_t)n * 32 + cc) = make_float2(ox, oy);
        }
    }
}

// ---------------- readout ----------------

__global__ void k_readout(const float* __restrict__ H3, const int* __restrict__ batch,
                          const float* __restrict__ lw, const float* __restrict__ lb,
                          float* __restrict__ pool, float* __restrict__ cnt, int n_nodes){
    __shared__ float pl[64];
    __shared__ float cl[64];
    if (threadIdx.x < 64){ pl[threadIdx.x] = 0.f; cl[threadIdx.x] = 0.f; }
    __syncthreads();
    int n = blockIdx.x * 256 + threadIdx.x;
    if (n < n_nodes){
        const float4* hp = (const float4*)(H3 + (size_t)n * 32);
        const float4* wp = (const float4*)lw;
        float y = 0.f;
        #pragma unroll
        for (int i = 0; i < 8; i++){
            float4 h4 = hp[i], w4 = wp[i];
            y += h4.x * w4.x + h4.y * w4.y + h4.z * w4.z + h4.w * w4.w;
        }
        y += lb[0];
        int b = batch[n];
        atomicAdd(&pl[b], y);
        atomicAdd(&cl[b], 1.f);
    }
    __syncthreads();
    if (threadIdx.x < 64 && cl[threadIdx.x] != 0.f){
        atomicAdd(&pool[threadIdx.x], pl[threadIdx.x]);
        atomicAdd(&cnt[threadIdx.x], cl[threadIdx.x]);
    }
}

__global__ void k_final(const float* __restrict__ pool, const float* __restrict__ cnt,
                        float* __restrict__ out){
    int g = threadIdx.x;
    if (g < 64) out[g] = (cnt[g] > 0.f) ? pool[g] / cnt[g] : 0.f;
}

// ---------------- launch ----------------

extern "C" void kernel_launch(void* const* d_in, const int* in_sizes, int n_in,
                              void* d_out, int out_size, void* d_ws, size_t ws_size,
                              hipStream_t stream){
    const float* x   = (const float*)d_in[0];
    const int*   ei  = (const int*)  d_in[1];
    const int*   bat = (const int*)  d_in[2];
    const float* W1  = (const float*)d_in[3];
    const float* a1s = (const float*)d_in[4];
    const float* a1d = (const float*)d_in[5];
    const float* b1  = (const float*)d_in[6];
    const float* W2  = (const float*)d_in[7];
    const float* a2s = (const float*)d_in[8];
    const float* a2d = (const float*)d_in[9];
    const float* b2  = (const float*)d_in[10];
    const float* W3  = (const float*)d_in[11];
    const float* a3s = (const float*)d_in[12];
    const float* a3d = (const float*)d_in[13];
    const float* b3  = (const float*)d_in[14];
    const float* lw  = (const float*)d_in[15];
    const float* lb  = (const float*)d_in[16];
    (void)n_in; (void)out_size; (void)ws_size;

    const int n_nodes = in_sizes[0] / D1;      // 100000
    const int n_edges = in_sizes[1] / 2;       // 1600000
    const int etot    = n_edges + n_nodes;     // 1700000
    const int nbin    = (n_nodes + BIN_NODES - 1) >> NODE_SHIFT;   // 196

    char* p = (char*)d_ws;
    size_t off = 0;
    auto alloc = [&](size_t bytes) -> char* {
        char* r = p + off;
        off = (off + bytes + 511) & ~(size_t)511;
        return r;
    };
    unsigned short* Hh   = (unsigned short*)alloc((size_t)n_nodes * 128 * 2); // 25.6 MB
    unsigned short* Xhi  = (unsigned short*)alloc((size_t)n_nodes * 128 * 2); // 25.6 MB
    unsigned short* Xlo  = (unsigned short*)alloc((size_t)n_nodes * 128 * 2); // 25.6 MB
    float*          asrc = (float*)alloc((size_t)n_nodes * 4 * 4);
    float*          adst = (float*)alloc((size_t)n_nodes * 4 * 4);
    unsigned short* Bp   = (unsigned short*)alloc(3 * 32768 * 2);
    int*   rowptr  = (int*)alloc((size_t)(n_nodes + 1) * 4);
    int*   eidx    = (int*)alloc((size_t)etot * 4);
    uint2* staged  = (uint2*)alloc((size_t)etot * 8);              // 13.6 MB
    int*   binCnt  = (int*)alloc(MAXBIN * 4);
    int*   binStart= (int*)alloc((MAXBIN + 1) * 4);
    int*   binCur  = (int*)alloc(MAXBIN * 4);
    float* pool    = (float*)alloc(64 * 4);
    float* cnt     = (float*)alloc(64 * 4);
    float* h3      = (float*)Xhi;              // alias: Xhi not read by layer-3 aggr

    hipMemsetAsync(binCnt, 0, MAXBIN * 4, stream);
    hipMemsetAsync(pool, 0, 64 * 4, stream);
    hipMemsetAsync(cnt, 0, 64 * 4, stream);

    k_prepw<<<192, 256, 0, stream>>>(W1, W2, W3, Bp);

    int cb = (etot + 4095) / 4096;             // 416 chunks
    kb_hist<<<cb, 256, 0, stream>>>(ei, binCnt, n_edges, etot, nbin);
    kb_scan<<<1, 64, 0, stream>>>(binCnt, binStart, binCur, nbin, rowptr, n_nodes, etot);
    kb_scatter<<<cb, 256, 0, stream>>>(ei, binCur, staged, n_edges, etot, nbin);
    kb_final<<<nbin, 512, 0, stream>>>(staged, binStart, rowptr, eidx, n_nodes);

    int mb = (n_nodes + 127) / 128;
    int rb = (n_nodes + 3) / 4;

    // layer 1 (reads fp32 x directly; split fused into mgemm)
    k_mgemm<1><<<mb, 256, 65536, stream>>>(x, nullptr, nullptr, Bp,
                                           a1s, a1d, Hh, asrc, adst, n_nodes);
    k_aggr<0><<<rb, 256, 0, stream>>>((const unsigned*)Hh, asrc, adst, rowptr, eidx,
                                      b1, Xhi, Xlo, nullptr, n_nodes);
    // layer 2
    k_mgemm<0><<<mb, 256, 65536, stream>>>(nullptr, Xhi, Xlo, Bp + 32768,
                                           a2s, a2d, Hh, asrc, adst, n_nodes);
    k_aggr<0><<<rb, 256, 0, stream>>>((const unsigned*)Hh, asrc, adst, rowptr, eidx,
                                      b2, Xhi, Xlo, nullptr, n_nodes);
    // layer 3
    k_mgemm<0><<<mb, 256, 65536, stream>>>(nullptr, Xhi, Xlo, Bp + 65536,
                                           a3s, a3d, Hh, asrc, adst, n_nodes);
    k_aggr<1><<<rb, 256, 0, stream>>>((const unsigned*)Hh, asrc, adst, rowptr, eidx,
                                      b3, nullptr, nullptr, h3, n_nodes);

    int ob = (n_nodes + 255) / 256;
    k_readout<<<ob, 256, 0, stream>>>(h3, bat, lw, lb, pool, cnt, n_nodes);
    k_final<<<1, 64, 0, stream>>>(pool, cnt, (float*)d_out);
}

// Round 11
// 545.653 us; speedup vs baseline: 1.0498x; 1.0498x over previous
//
#include <hip/hip_runtime.h>
#include <hip/hip_fp16.h>
#include <math.h>

#define D1 128
#define NEG 0.2f
#define NODE_SHIFT 9
#define BIN_NODES 512
#define MAXBIN 256

typedef short v8s __attribute__((ext_vector_type(8)));
typedef float v4f __attribute__((ext_vector_type(4)));

__device__ __forceinline__ float lrelu(float v){ return v > 0.f ? v : NEG * v; }
__device__ __forceinline__ float elu_f(float v){ return v > 0.f ? v : __expf(v) - 1.f; }

__device__ __forceinline__ unsigned short bf16s(float f){
    unsigned u = __float_as_uint(f);
    return (unsigned short)((u + 0x7fffu + ((u >> 16) & 1u)) >> 16);   // RNE
}
__device__ __forceinline__ float bf2f(unsigned short s){
    return __uint_as_float(((unsigned)s) << 16);
}
__device__ __forceinline__ unsigned f2h2(float a, float b){           // a->low, b->high
    return ((unsigned)__half_as_ushort(__float2half_rn(b)) << 16) |
           (unsigned)__half_as_ushort(__float2half_rn(a));
}
__device__ __forceinline__ float2 h2f2(unsigned u){
    float lo = __half2float(__ushort_as_half((unsigned short)(u & 0xffffu)));
    float hi = __half2float(__ushort_as_half((unsigned short)(u >> 16)));
    return make_float2(lo, hi);
}
__device__ __forceinline__ void split8(const float* f, v8s& hi, v8s& lo){
    #pragma unroll
    for (int i = 0; i < 8; i++){
        unsigned short h = bf16s(f[i]);
        ((short*)&hi)[i] = (short)h;
        ((short*)&lo)[i] = (short)bf16s(f[i] - bf2f(h));
    }
}

// ---------------- binned CSR build ----------------
// staged entry: (dstLow << 17) | src   (src < 2^17, dstLow < 2^9)

__global__ __launch_bounds__(256) void kb_hist(const int* __restrict__ ei,
                                               int* __restrict__ binCnt,
                                               int n_edges, int etot, int nbin){
    __shared__ int h[MAXBIN];
    for (int i = threadIdx.x; i < nbin; i += 256) h[i] = 0;
    __syncthreads();
    int stride = gridDim.x * 256;
    for (int e = blockIdx.x * 256 + threadIdx.x; e < etot; e += stride){
        int dst = (e < n_edges) ? ei[n_edges + e] : (e - n_edges);
        atomicAdd(&h[dst >> NODE_SHIFT], 1);
    }
    __syncthreads();
    for (int i = threadIdx.x; i < nbin; i += 256)
        if (h[i]) atomicAdd(&binCnt[i], h[i]);
}

__global__ void kb_scan(const int* __restrict__ binCnt, int* __restrict__ binStart,
                        int* __restrict__ binCursor, int nbin,
                        int* __restrict__ rowptr, int n_nodes, int etot){
    if (threadIdx.x == 0){
        int run = 0;
        for (int b = 0; b < nbin; b++){
            binStart[b] = run; binCursor[b] = run; run += binCnt[b];
        }
        binStart[nbin] = run;
        rowptr[n_nodes] = etot;
    }
}

__global__ __launch_bounds__(256) void kb_scatter(const int* __restrict__ ei,
                                                  int* __restrict__ binCursor,
                                                  unsigned* __restrict__ staged,
                                                  int n_edges, int etot, int nbin){
    __shared__ int cnt[MAXBIN];
    __shared__ int base[MAXBIN];
    int e0 = blockIdx.x * 4096;
    for (int i = threadIdx.x; i < nbin; i += 256) cnt[i] = 0;
    __syncthreads();
    #pragma unroll 4
    for (int r = 0; r < 16; r++){
        int e = e0 + r * 256 + threadIdx.x;
        if (e < etot){
            int dst = (e < n_edges) ? ei[n_edges + e] : (e - n_edges);
            atomicAdd(&cnt[dst >> NODE_SHIFT], 1);
        }
    }
    __syncthreads();
    for (int i = threadIdx.x; i < nbin; i += 256){
        base[i] = cnt[i] ? atomicAdd(&binCursor[i], cnt[i]) : 0;
        cnt[i] = 0;
    }
    __syncthreads();
    #pragma unroll 4
    for (int r = 0; r < 16; r++){
        int e = e0 + r * 256 + threadIdx.x;
        if (e < etot){
            int src, dst;
            if (e < n_edges){ src = ei[e]; dst = ei[n_edges + e]; }
            else            { src = dst = e - n_edges; }
            int b = dst >> NODE_SHIFT;
            int p = base[b] + atomicAdd(&cnt[b], 1);
            staged[p] = ((unsigned)(dst & (BIN_NODES - 1)) << 17) | (unsigned)src;
        }
    }
}

__global__ __launch_bounds__(512) void kb_final(const unsigned* __restrict__ staged,
                                                const int* __restrict__ binStart,
                                                int* __restrict__ rowptr,
                                                int* __restrict__ eidx, int n_nodes){
    __shared__ int deg[BIN_NODES];
    __shared__ int cur[BIN_NODES];
    int b = blockIdx.x;
    int nbase = b << NODE_SHIFT;
    int s0 = binStart[b], s1 = binStart[b + 1];
    deg[threadIdx.x] = 0;
    __syncthreads();
    for (int i = s0 + threadIdx.x; i < s1; i += 512)
        atomicAdd(&deg[staged[i] >> 17], 1);
    __syncthreads();
    int v = deg[threadIdx.x];
    cur[threadIdx.x] = v;
    __syncthreads();
    for (int off = 1; off < BIN_NODES; off <<= 1){
        int t = (threadIdx.x >= off) ? cur[threadIdx.x - off] : 0;
        __syncthreads();
        cur[threadIdx.x] += t;
        __syncthreads();
    }
    int excl = cur[threadIdx.x] - v;           // exclusive prefix within bin
    int node = nbase + threadIdx.x;
    if (node < n_nodes) rowptr[node] = s0 + excl;
    cur[threadIdx.x] = s0 + excl;              // becomes cursor
    __syncthreads();
    for (int i = s0 + threadIdx.x; i < s1; i += 512){
        unsigned pr = staged[i];
        int p = atomicAdd(&cur[pr >> 17], 1);
        eidx[p] = (int)(pr & 0x1FFFFu);
    }
}

// ---------------- weight prep: split W into bf16 hi/lo, k-packed B' layout ----

__global__ void k_prepw(const float* __restrict__ W1, const float* __restrict__ W2,
                        const float* __restrict__ W3, unsigned short* __restrict__ Bp){
    int t = blockIdx.x * 256 + threadIdx.x;          // 0..49151
    if (t >= 49152) return;
    int w = t >> 14;
    int r = t & 16383;
    int k = r >> 7, j = r & 127;
    const float* W = (w == 0) ? W1 : (w == 1) ? W2 : W3;
    float val = W[j * 128 + k];
    unsigned short hi = bf16s(val);
    unsigned short lo = bf16s(val - bf2f(hi));
    int idx = (k >> 3) * 1024 + j * 8 + (k & 7);
    Bp[w * 32768 + idx] = hi;
    Bp[w * 32768 + 16384 + idx] = lo;
}

// ---------------- split-bf16 MFMA GEMM + fused attention coefficients --------
// v5 = round-9 v3 structure (2 groups x 2 K-slices, 32 KB LDS, 4 waves/SIMD)
// + FP32SRC: layer-1 reads fp32 x directly, splits to bf16 hi/lo in registers.

template<int FP32SRC>
__global__ __launch_bounds__(256, 4) void k_mgemm(
        const float* __restrict__ Xf,
        const unsigned short* __restrict__ Xhi, const unsigned short* __restrict__ Xlo,
        const unsigned short* __restrict__ Bp,
        const float* __restrict__ aw_s, const float* __restrict__ aw_d,
        unsigned short* __restrict__ Hh,
        float* __restrict__ asrc, float* __restrict__ adst, int n_rows){
    __shared__ unsigned short Bs[16384];         // 32 KB: hi[8192] + lo[8192], 2 K-slices
    int lane = threadIdx.x & 63;
    int wv   = threadIdx.x >> 6;
    int li = lane & 15, quad = lane >> 4;
    int r0 = blockIdx.x * 128 + wv * 32;

    int row0 = r0 + li;
    int row1 = r0 + 16 + li;
    int rc0 = row0 < n_rows ? row0 : 0;
    int rc1 = row1 < n_rows ? row1 : 0;

    v4f acc[2][8];
    #pragma unroll
    for (int m = 0; m < 2; m++)
        #pragma unroll
        for (int t = 0; t < 8; t++)
            acc[m][t] = (v4f){0.f, 0.f, 0.f, 0.f};

    #pragma unroll
    for (int g = 0; g < 2; g++){
        if (g) __syncthreads();
        // stage 2 K-slices: hi 8192 shorts + lo 8192 shorts (2048 float4 total)
        #pragma unroll
        for (int i = 0; i < 4; i++){
            int idx = threadIdx.x + i * 256;
            ((float4*)Bs)[idx]          = ((const float4*)(Bp + g * 8192))[idx];
            ((float4*)(Bs + 8192))[idx] = ((const float4*)(Bp + 16384 + g * 8192))[idx];
        }
        __syncthreads();
        #pragma unroll
        for (int ks2 = 0; ks2 < 2; ks2++){
            int ks = g * 2 + ks2;
            int koff = ks * 32 + quad * 8;
            v8s ah0, al0, ah1, al1;
            if (FP32SRC){
                float f0[8], f1[8];
                *(float4*)&f0[0] = *(const float4*)(Xf + (size_t)rc0 * 128 + koff);
                *(float4*)&f0[4] = *(const float4*)(Xf + (size_t)rc0 * 128 + koff + 4);
                *(float4*)&f1[0] = *(const float4*)(Xf + (size_t)rc1 * 128 + koff);
                *(float4*)&f1[4] = *(const float4*)(Xf + (size_t)rc1 * 128 + koff + 4);
                split8(f0, ah0, al0);
                split8(f1, ah1, al1);
            } else {
                ah0 = *(const v8s*)(Xhi + (size_t)rc0 * 128 + koff);
                al0 = *(const v8s*)(Xlo + (size_t)rc0 * 128 + koff);
                ah1 = *(const v8s*)(Xhi + (size_t)rc1 * 128 + koff);
                al1 = *(const v8s*)(Xlo + (size_t)rc1 * 128 + koff);
            }
            #pragma unroll
            for (int t = 0; t < 8; t++){
                int bo = ks2 * 4096 + quad * 1024 + (t * 16 + li) * 8;
                v8s bh = *(const v8s*)(Bs + bo);
                v8s bl = *(const v8s*)(Bs + 8192 + bo);
                acc[0][t] = __builtin_amdgcn_mfma_f32_16x16x32_bf16(ah0, bh, acc[0][t], 0, 0, 0);
                acc[0][t] = __builtin_amdgcn_mfma_f32_16x16x32_bf16(ah0, bl, acc[0][t], 0, 0, 0);
                acc[0][t] = __builtin_amdgcn_mfma_f32_16x16x32_bf16(al0, bh, acc[0][t], 0, 0, 0);
                acc[1][t] = __builtin_amdgcn_mfma_f32_16x16x32_bf16(ah1, bh, acc[1][t], 0, 0, 0);
                acc[1][t] = __builtin_amdgcn_mfma_f32_16x16x32_bf16(ah1, bl, acc[1][t], 0, 0, 0);
                acc[1][t] = __builtin_amdgcn_mfma_f32_16x16x32_bf16(al1, bh, acc[1][t], 0, 0, 0);
            }
        }
    }

    // epilogue 1: fp16 mirror
    #pragma unroll
    for (int m = 0; m < 2; m++){
        #pragma unroll
        for (int t = 0; t < 8; t++){
            #pragma unroll
            for (int r = 0; r < 4; r++){
                float v  = acc[m][t][r];
                float vo = __shfl_xor(v, 1);
                if (!(li & 1)){
                    int row = r0 + m * 16 + quad * 4 + r;
                    if (row < n_rows)
                        *(unsigned*)(Hh + (size_t)row * 128 + t * 16 + li) = f2h2(v, vo);
                }
            }
        }
    }

    // epilogue 2: fused attention coefficients
    float as8[8], ad8[8];
    #pragma unroll
    for (int t = 0; t < 8; t++){
        as8[t] = aw_s[t * 16 + li];
        ad8[t] = aw_d[t * 16 + li];
    }
    #pragma unroll
    for (int m = 0; m < 2; m++){
        #pragma unroll
        for (int r = 0; r < 4; r++){
            float sp[4], dp[4];
            #pragma unroll
            for (int h = 0; h < 4; h++){
                sp[h] = acc[m][2*h][r] * as8[2*h] + acc[m][2*h+1][r] * as8[2*h+1];
                dp[h] = acc[m][2*h][r] * ad8[2*h] + acc[m][2*h+1][r] * ad8[2*h+1];
            }
            #pragma unroll
            for (int off = 1; off < 16; off <<= 1){
                #pragma unroll
                for (int h = 0; h < 4; h++){
                    sp[h] += __shfl_xor(sp[h], off);
                    dp[h] += __shfl_xor(dp[h], off);
                }
            }
            if (li == 0){
                int row = r0 + m * 16 + quad * 4 + r;
                if (row < n_rows){
                    ((float4*)asrc)[row] = make_float4(sp[0], sp[1], sp[2], sp[3]);
                    ((float4*)adst)[row] = make_float4(dp[0], dp[1], dp[2], dp[3]);
                }
            }
        }
    }
}

// ---------------- fused softmax + aggregation, one wave per node ----------------
// Single pass, per-lane private denominator. Exp dedup: per 8-edge batch, lanes
// 0..31 each compute ONE (edge,head) weight; head groups fetch all 8 via shfl.

template<int MEAN>
__global__ __launch_bounds__(256) void k_aggr(
        const unsigned* __restrict__ Hh,
        const float* __restrict__ asrc, const float* __restrict__ adst,
        const int* __restrict__ rowptr, const int* __restrict__ eidx,
        const float* __restrict__ bias,
        unsigned short* __restrict__ Oh, unsigned short* __restrict__ Ol,
        float* __restrict__ Of, int n_nodes){
    int lane = threadIdx.x & 63;
    int wid  = threadIdx.x >> 6;
    int n = blockIdx.x * 4 + wid;
    if (n >= n_nodes) return;
    int row0 = rowptr[n];
    int deg  = rowptr[n + 1] - row0;
    const int* ep = eidx + row0;
    unsigned hd = (unsigned)(lane >> 4);          // this lane's head
    unsigned ul = (unsigned)lane;
    float4 ad = ((const float4*)adst)[n];
    float adh = hd == 0 ? ad.x : hd == 1 ? ad.y : hd == 2 ? ad.z : ad.w;
    unsigned wh = (ul >> 3) & 3;                  // w-computation role head
    float adw = wh == 0 ? ad.x : wh == 1 ? ad.y : wh == 2 ? ad.z : ad.w;
    int wsrc = (int)(hd * 8);                     // shfl source base

    float accx = 0.f, accy = 0.f, den = 0.f;
    int i = 0;
    for (; i + 8 <= deg; i += 8){
        unsigned s[8];
        #pragma unroll
        for (int j = 0; j < 8; j++) s[j] = (unsigned)ep[i + j];
        float aW = asrc[s[ul & 7] * 4u + wh];
        float w = __expf(lrelu(aW + adw));
        unsigned hw[8];
        #pragma unroll
        for (int j = 0; j < 8; j++) hw[j] = Hh[s[j] * 64u + ul];
        #pragma unroll
        for (int j = 0; j < 8; j++){
            float wj = __shfl(w, wsrc + j);
            float2 hv = h2f2(hw[j]);
            den  += wj;
            accx += wj * hv.x;
            accy += wj * hv.y;
        }
    }
    for (; i < deg; i++){
        unsigned s = (unsigned)ep[i];
        float w = __expf(lrelu(asrc[s * 4u + hd] + adh));
        float2 hv = h2f2(Hh[s * 64u + ul]);
        den  += w;
        accx += w * hv.x;
        accy += w * hv.y;
    }
    float rdh = 1.f / den;
    accx *= rdh; accy *= rdh;

    int c = lane * 2;
    if (!MEAN){
        float ox = elu_f(accx + bias[c]);
        float oy = elu_f(accy + bias[c + 1]);
        unsigned short hx = bf16s(ox), hy = bf16s(oy);
        unsigned short lx = bf16s(ox - bf2f(hx)), ly = bf16s(oy - bf2f(hy));
        *(ushort2*)(Oh + (size_t)n * 128 + c) = make_ushort2(hx, hy);
        *(ushort2*)(Ol + (size_t)n * 128 + c) = make_ushort2(lx, ly);
    } else {
        float sx = accx, sy = accy;
        sx += __shfl_xor(sx, 16); sy += __shfl_xor(sy, 16);
        sx += __shfl_xor(sx, 32); sy += __shfl_xor(sy, 32);
        if (lane < 16){
            int cc = lane * 2;
            float ox = elu_f(sx * 0.25f + bias[cc]);
            float oy = elu_f(sy * 0.25f + bias[cc + 1]);
            *(float2*)(Of + (size_t)n * 32 + cc) = make_float2(ox, oy);
        }
    }
}

// ---------------- readout ----------------

__global__ void k_readout(const float* __restrict__ H3, const int* __restrict__ batch,
                          const float* __restrict__ lw, const float* __restrict__ lb,
                          float* __restrict__ pool, float* __restrict__ cnt, int n_nodes){
    __shared__ float pl[64];
    __shared__ float cl[64];
    if (threadIdx.x < 64){ pl[threadIdx.x] = 0.f; cl[threadIdx.x] = 0.f; }
    __syncthreads();
    int n = blockIdx.x * 256 + threadIdx.x;
    if (n < n_nodes){
        const float4* hp = (const float4*)(H3 + (size_t)n * 32);
        const float4* wp = (const float4*)lw;
        float y = 0.f;
        #pragma unroll
        for (int i = 0; i < 8; i++){
            float4 h4 = hp[i], w4 = wp[i];
            y += h4.x * w4.x + h4.y * w4.y + h4.z * w4.z + h4.w * w4.w;
        }
        y += lb[0];
        int b = batch[n];
        atomicAdd(&pl[b], y);
        atomicAdd(&cl[b], 1.f);
    }
    __syncthreads();
    if (threadIdx.x < 64 && cl[threadIdx.x] != 0.f){
        atomicAdd(&pool[threadIdx.x], pl[threadIdx.x]);
        atomicAdd(&cnt[threadIdx.x], cl[threadIdx.x]);
    }
}

__global__ void k_final(const float* __restrict__ pool, const float* __restrict__ cnt,
                        float* __restrict__ out){
    int g = threadIdx.x;
    if (g < 64) out[g] = (cnt[g] > 0.f) ? pool[g] / cnt[g] : 0.f;
}

// ---------------- launch ----------------

extern "C" void kernel_launch(void* const* d_in, const int* in_sizes, int n_in,
                              void* d_out, int out_size, void* d_ws, size_t ws_size,
                              hipStream_t stream){
    const float* x   = (const float*)d_in[0];
    const int*   ei  = (const int*)  d_in[1];
    const int*   bat = (const int*)  d_in[2];
    const float* W1  = (const float*)d_in[3];
    const float* a1s = (const float*)d_in[4];
    const float* a1d = (const float*)d_in[5];
    const float* b1  = (const float*)d_in[6];
    const float* W2  = (const float*)d_in[7];
    const float* a2s = (const float*)d_in[8];
    const float* a2d = (const float*)d_in[9];
    const float* b2  = (const float*)d_in[10];
    const float* W3  = (const float*)d_in[11];
    const float* a3s = (const float*)d_in[12];
    const float* a3d = (const float*)d_in[13];
    const float* b3  = (const float*)d_in[14];
    const float* lw  = (const float*)d_in[15];
    const float* lb  = (const float*)d_in[16];
    (void)n_in; (void)out_size; (void)ws_size;

    const int n_nodes = in_sizes[0] / D1;      // 100000
    const int n_edges = in_sizes[1] / 2;       // 1600000
    const int etot    = n_edges + n_nodes;     // 1700000
    const int nbin    = (n_nodes + BIN_NODES - 1) >> NODE_SHIFT;   // 196

    char* p = (char*)d_ws;
    size_t off = 0;
    auto alloc = [&](size_t bytes) -> char* {
        char* r = p + off;
        off = (off + bytes + 511) & ~(size_t)511;
        return r;
    };
    unsigned short* Hh   = (unsigned short*)alloc((size_t)n_nodes * 128 * 2); // 25.6 MB
    unsigned short* Xhi  = (unsigned short*)alloc((size_t)n_nodes * 128 * 2); // 25.6 MB
    unsigned short* Xlo  = (unsigned short*)alloc((size_t)n_nodes * 128 * 2); // 25.6 MB
    float*          asrc = (float*)alloc((size_t)n_nodes * 4 * 4);
    float*          adst = (float*)alloc((size_t)n_nodes * 4 * 4);
    unsigned short* Bp   = (unsigned short*)alloc(3 * 32768 * 2);
    int*      rowptr  = (int*)alloc((size_t)(n_nodes + 1) * 4);
    int*      eidx    = (int*)alloc((size_t)etot * 4);
    unsigned* staged  = (unsigned*)alloc((size_t)etot * 4);        // 6.8 MB packed
    int*      binCnt  = (int*)alloc(MAXBIN * 4);
    int*      binStart= (int*)alloc((MAXBIN + 1) * 4);
    int*      binCur  = (int*)alloc(MAXBIN * 4);
    float*    pool    = (float*)alloc(64 * 4);
    float*    cnt     = (float*)alloc(64 * 4);
    float*    h3      = (float*)Xhi;           // alias: Xhi not read by layer-3 aggr

    hipMemsetAsync(binCnt, 0, MAXBIN * 4, stream);
    hipMemsetAsync(pool, 0, 64 * 4, stream);
    hipMemsetAsync(cnt, 0, 64 * 4, stream);

    k_prepw<<<192, 256, 0, stream>>>(W1, W2, W3, Bp);

    int cb = (etot + 4095) / 4096;             // 416 chunks
    kb_hist<<<cb, 256, 0, stream>>>(ei, binCnt, n_edges, etot, nbin);
    kb_scan<<<1, 64, 0, stream>>>(binCnt, binStart, binCur, nbin, rowptr, n_nodes, etot);
    kb_scatter<<<cb, 256, 0, stream>>>(ei, binCur, staged, n_edges, etot, nbin);
    kb_final<<<nbin, 512, 0, stream>>>(staged, binStart, rowptr, eidx, n_nodes);

    int mb = (n_nodes + 127) / 128;
    int rb = (n_nodes + 3) / 4;

    // layer 1 (reads fp32 x directly; split fused into mgemm)
    k_mgemm<1><<<mb, 256, 0, stream>>>(x, nullptr, nullptr, Bp,
                                       a1s, a1d, Hh, asrc, adst, n_nodes);
    k_aggr<0><<<rb, 256, 0, stream>>>((const unsigned*)Hh, asrc, adst, rowptr, eidx,
                                      b1, Xhi, Xlo, nullptr, n_nodes);
    // layer 2
    k_mgemm<0><<<mb, 256, 0, stream>>>(nullptr, Xhi, Xlo, Bp + 32768,
                                       a2s, a2d, Hh, asrc, adst, n_nodes);
    k_aggr<0><<<rb, 256, 0, stream>>>((const unsigned*)Hh, asrc, adst, rowptr, eidx,
                                      b2, Xhi, Xlo, nullptr, n_nodes);
    // layer 3
    k_mgemm<0><<<mb, 256, 0, stream>>>(nullptr, Xhi, Xlo, Bp + 65536,
                                       a3s, a3d, Hh, asrc, adst, n_nodes);
    k_aggr<1><<<rb, 256, 0, stream>>>((const unsigned*)Hh, asrc, adst, rowptr, eidx,
                                      b3, nullptr, nullptr, h3, n_nodes);

    int ob = (n_nodes + 255) / 256;
    k_readout<<<ob, 256, 0, stream>>>(h3, bat, lw, lb, pool, cnt, n_nodes);
    k_final<<<1, 64, 0, stream>>>(pool, cnt, (float*)d_out);
}

// Round 12
// 522.621 us; speedup vs baseline: 1.0960x; 1.0441x over previous
//
#include <hip/hip_runtime.h>
#include <hip/hip_fp16.h>
#include <math.h>

#define D1 128
#define NEG 0.2f
#define NODE_SHIFT 9
#define BIN_NODES 512
#define MAXBIN 256

typedef _Float16 v8h __attribute__((ext_vector_type(8)));
typedef float v4f __attribute__((ext_vector_type(4)));

__device__ __forceinline__ float lrelu(float v){ return v > 0.f ? v : NEG * v; }
__device__ __forceinline__ float elu_f(float v){ return v > 0.f ? v : __expf(v) - 1.f; }

__device__ __forceinline__ unsigned f2h2(float a, float b){           // a->low, b->high
    return ((unsigned)__half_as_ushort(__float2half_rn(b)) << 16) |
           (unsigned)__half_as_ushort(__float2half_rn(a));
}
__device__ __forceinline__ float2 h2f2(unsigned u){
    float lo = __half2float(__ushort_as_half((unsigned short)(u & 0xffffu)));
    float hi = __half2float(__ushort_as_half((unsigned short)(u >> 16)));
    return make_float2(lo, hi);
}

// ---------------- binned CSR build ----------------
// staged entry: (dstLow << 17) | src   (src < 2^17, dstLow < 2^9)

__global__ __launch_bounds__(256) void kb_hist(const int* __restrict__ ei,
                                               int* __restrict__ binCnt,
                                               int n_edges, int etot, int nbin){
    __shared__ int h[MAXBIN];
    for (int i = threadIdx.x; i < nbin; i += 256) h[i] = 0;
    __syncthreads();
    int stride = gridDim.x * 256;
    for (int e = blockIdx.x * 256 + threadIdx.x; e < etot; e += stride){
        int dst = (e < n_edges) ? ei[n_edges + e] : (e - n_edges);
        atomicAdd(&h[dst >> NODE_SHIFT], 1);
    }
    __syncthreads();
    for (int i = threadIdx.x; i < nbin; i += 256)
        if (h[i]) atomicAdd(&binCnt[i], h[i]);
}

__global__ void kb_scan(const int* __restrict__ binCnt, int* __restrict__ binStart,
                        int* __restrict__ binCursor, int nbin,
                        int* __restrict__ rowptr, int n_nodes, int etot){
    if (threadIdx.x == 0){
        int run = 0;
        for (int b = 0; b < nbin; b++){
            binStart[b] = run; binCursor[b] = run; run += binCnt[b];
        }
        binStart[nbin] = run;
        rowptr[n_nodes] = etot;
    }
}

__global__ __launch_bounds__(256) void kb_scatter(const int* __restrict__ ei,
                                                  int* __restrict__ binCursor,
                                                  unsigned* __restrict__ staged,
                                                  int n_edges, int etot, int nbin){
    __shared__ int cnt[MAXBIN];
    __shared__ int base[MAXBIN];
    int e0 = blockIdx.x * 4096;
    for (int i = threadIdx.x; i < nbin; i += 256) cnt[i] = 0;
    __syncthreads();
    #pragma unroll 4
    for (int r = 0; r < 16; r++){
        int e = e0 + r * 256 + threadIdx.x;
        if (e < etot){
            int dst = (e < n_edges) ? ei[n_edges + e] : (e - n_edges);
            atomicAdd(&cnt[dst >> NODE_SHIFT], 1);
        }
    }
    __syncthreads();
    for (int i = threadIdx.x; i < nbin; i += 256){
        base[i] = cnt[i] ? atomicAdd(&binCursor[i], cnt[i]) : 0;
        cnt[i] = 0;
    }
    __syncthreads();
    #pragma unroll 4
    for (int r = 0; r < 16; r++){
        int e = e0 + r * 256 + threadIdx.x;
        if (e < etot){
            int src, dst;
            if (e < n_edges){ src = ei[e]; dst = ei[n_edges + e]; }
            else            { src = dst = e - n_edges; }
            int b = dst >> NODE_SHIFT;
            int p = base[b] + atomicAdd(&cnt[b], 1);
            staged[p] = ((unsigned)(dst & (BIN_NODES - 1)) << 17) | (unsigned)src;
        }
    }
}

__global__ __launch_bounds__(512) void kb_final(const unsigned* __restrict__ staged,
                                                const int* __restrict__ binStart,
                                                int* __restrict__ rowptr,
                                                int* __restrict__ eidx, int n_nodes){
    __shared__ int deg[BIN_NODES];
    __shared__ int cur[BIN_NODES];
    int b = blockIdx.x;
    int nbase = b << NODE_SHIFT;
    int s0 = binStart[b], s1 = binStart[b + 1];
    deg[threadIdx.x] = 0;
    __syncthreads();
    for (int i = s0 + threadIdx.x; i < s1; i += 512)
        atomicAdd(&deg[staged[i] >> 17], 1);
    __syncthreads();
    int v = deg[threadIdx.x];
    cur[threadIdx.x] = v;
    __syncthreads();
    for (int off = 1; off < BIN_NODES; off <<= 1){
        int t = (threadIdx.x >= off) ? cur[threadIdx.x - off] : 0;
        __syncthreads();
        cur[threadIdx.x] += t;
        __syncthreads();
    }
    int excl = cur[threadIdx.x] - v;           // exclusive prefix within bin
    int node = nbase + threadIdx.x;
    if (node < n_nodes) rowptr[node] = s0 + excl;
    cur[threadIdx.x] = s0 + excl;              // becomes cursor
    __syncthreads();
    for (int i = s0 + threadIdx.x; i < s1; i += 512){
        unsigned pr = staged[i];
        int p = atomicAdd(&cur[pr >> 17], 1);
        eidx[p] = (int)(pr & 0x1FFFFu);
    }
}

// ---------------- weight prep: f16 W, k-packed B' layout ----------------
// B[k][j] = W[j][k].  B'[kb][j][kk], kb=k>>3, kk=k&7 (f16 bits in ushort).

__global__ void k_prepw(const float* __restrict__ W1, const float* __restrict__ W2,
                        const float* __restrict__ W3, unsigned short* __restrict__ Bp){
    int t = blockIdx.x * 256 + threadIdx.x;          // 0..49151
    if (t >= 49152) return;
    int w = t >> 14;
    int r = t & 16383;
    int k = r >> 7, j = r & 127;
    const float* W = (w == 0) ? W1 : (w == 1) ? W2 : W3;
    float val = W[j * 128 + k];
    int idx = (k >> 3) * 1024 + j * 8 + (k & 7);
    Bp[w * 16384 + idx] = __half_as_ushort(__float2half_rn(val));
}

// ---------------- f16 MFMA GEMM + fused attention coefficients ----------------
// H = X @ W.T, all operands fp16, fp32 accumulate. A fragments fully hoisted
// (8 x v8h = 32 VGPR), B staged once in 32 KB LDS, one barrier, 64-MFMA stream.
// mfma_f32_16x16x32_f16: A[m=lane&15][k=quad*8+j]; C/D[row=quad*4+reg][col=lane&15].

template<int FP32SRC>
__global__ __launch_bounds__(256, 4) void k_mgemm(
        const float* __restrict__ Xf, const unsigned short* __restrict__ Xh,
        const unsigned short* __restrict__ Bp,
        const float* __restrict__ aw_s, const float* __restrict__ aw_d,
        unsigned short* __restrict__ Hh,
        float* __restrict__ asrc, float* __restrict__ adst, int n_rows){
    __shared__ unsigned short Bs[16384];         // 32 KB: whole B panel, f16
    int lane = threadIdx.x & 63;
    int wv   = threadIdx.x >> 6;
    int li = lane & 15, quad = lane >> 4;
    int r0 = blockIdx.x * 128 + wv * 32;

    int row0 = r0 + li;
    int row1 = r0 + 16 + li;
    int rc0 = row0 < n_rows ? row0 : 0;
    int rc1 = row1 < n_rows ? row1 : 0;

    // hoist all A fragments (independent of LDS staging)
    v8h a0[4], a1[4];
    #pragma unroll
    for (int ks = 0; ks < 4; ks++){
        int koff = ks * 32 + quad * 8;
        if (FP32SRC){
            float f0[8], f1[8];
            *(float4*)&f0[0] = *(const float4*)(Xf + (size_t)rc0 * 128 + koff);
            *(float4*)&f0[4] = *(const float4*)(Xf + (size_t)rc0 * 128 + koff + 4);
            *(float4*)&f1[0] = *(const float4*)(Xf + (size_t)rc1 * 128 + koff);
            *(float4*)&f1[4] = *(const float4*)(Xf + (size_t)rc1 * 128 + koff + 4);
            #pragma unroll
            for (int i = 0; i < 8; i++){
                a0[ks][i] = (_Float16)f0[i];
                a1[ks][i] = (_Float16)f1[i];
            }
        } else {
            a0[ks] = *(const v8h*)(Xh + (size_t)rc0 * 128 + koff);
            a1[ks] = *(const v8h*)(Xh + (size_t)rc1 * 128 + koff);
        }
    }

    // stage whole B panel: 2048 float4, 8 per thread
    #pragma unroll
    for (int i = 0; i < 8; i++){
        int idx = threadIdx.x + i * 256;
        ((float4*)Bs)[idx] = ((const float4*)Bp)[idx];
    }
    __syncthreads();

    v4f acc[2][8];
    #pragma unroll
    for (int m = 0; m < 2; m++)
        #pragma unroll
        for (int t = 0; t < 8; t++)
            acc[m][t] = (v4f){0.f, 0.f, 0.f, 0.f};

    #pragma unroll
    for (int ks = 0; ks < 4; ks++){
        #pragma unroll
        for (int t = 0; t < 8; t++){
            int bo = (ks * 4 + quad) * 1024 + (t * 16 + li) * 8;
            v8h b = *(const v8h*)(Bs + bo);
            acc[0][t] = __builtin_amdgcn_mfma_f32_16x16x32_f16(a0[ks], b, acc[0][t], 0, 0, 0);
            acc[1][t] = __builtin_amdgcn_mfma_f32_16x16x32_f16(a1[ks], b, acc[1][t], 0, 0, 0);
        }
    }

    // epilogue 1: fp16 mirror
    #pragma unroll
    for (int m = 0; m < 2; m++){
        #pragma unroll
        for (int t = 0; t < 8; t++){
            #pragma unroll
            for (int r = 0; r < 4; r++){
                float v  = acc[m][t][r];
                float vo = __shfl_xor(v, 1);
                if (!(li & 1)){
                    int row = r0 + m * 16 + quad * 4 + r;
                    if (row < n_rows)
                        *(unsigned*)(Hh + (size_t)row * 128 + t * 16 + li) = f2h2(v, vo);
                }
            }
        }
    }

    // epilogue 2: fused attention coefficients (fp32)
    float as8[8], ad8[8];
    #pragma unroll
    for (int t = 0; t < 8; t++){
        as8[t] = aw_s[t * 16 + li];
        ad8[t] = aw_d[t * 16 + li];
    }
    #pragma unroll
    for (int m = 0; m < 2; m++){
        #pragma unroll
        for (int r = 0; r < 4; r++){
            float sp[4], dp[4];
            #pragma unroll
            for (int h = 0; h < 4; h++){
                sp[h] = acc[m][2*h][r] * as8[2*h] + acc[m][2*h+1][r] * as8[2*h+1];
                dp[h] = acc[m][2*h][r] * ad8[2*h] + acc[m][2*h+1][r] * ad8[2*h+1];
            }
            #pragma unroll
            for (int off = 1; off < 16; off <<= 1){
                #pragma unroll
                for (int h = 0; h < 4; h++){
                    sp[h] += __shfl_xor(sp[h], off);
                    dp[h] += __shfl_xor(dp[h], off);
                }
            }
            if (li == 0){
                int row = r0 + m * 16 + quad * 4 + r;
                if (row < n_rows){
                    ((float4*)asrc)[row] = make_float4(sp[0], sp[1], sp[2], sp[3]);
                    ((float4*)adst)[row] = make_float4(dp[0], dp[1], dp[2], dp[3]);
                }
            }
        }
    }
}

// ---------------- fused softmax + aggregation, one wave per node ----------------
// Single pass, per-lane private denominator, exp-dedup via shfl. MEAN=0 writes
// one fp16 array (next GEMM input = gather format); MEAN=1 writes fp32 [n][32].

template<int MEAN>
__global__ __launch_bounds__(256) void k_aggr(
        const unsigned* __restrict__ Hh,
        const float* __restrict__ asrc, const float* __restrict__ adst,
        const int* __restrict__ rowptr, const int* __restrict__ eidx,
        const float* __restrict__ bias,
        unsigned short* __restrict__ O, float* __restrict__ Of, int n_nodes){
    int lane = threadIdx.x & 63;
    int wid  = threadIdx.x >> 6;
    int n = blockIdx.x * 4 + wid;
    if (n >= n_nodes) return;
    int row0 = rowptr[n];
    int deg  = rowptr[n + 1] - row0;
    const int* ep = eidx + row0;
    unsigned hd = (unsigned)(lane >> 4);          // this lane's head
    unsigned ul = (unsigned)lane;
    float4 ad = ((const float4*)adst)[n];
    float adh = hd == 0 ? ad.x : hd == 1 ? ad.y : hd == 2 ? ad.z : ad.w;
    unsigned wh = (ul >> 3) & 3;                  // w-computation role head
    float adw = wh == 0 ? ad.x : wh == 1 ? ad.y : wh == 2 ? ad.z : ad.w;
    int wsrc = (int)(hd * 8);                     // shfl source base

    float accx = 0.f, accy = 0.f, den = 0.f;
    int i = 0;
    for (; i + 8 <= deg; i += 8){
        unsigned s[8];
        #pragma unroll
        for (int j = 0; j < 8; j++) s[j] = (unsigned)ep[i + j];
        float aW = asrc[s[ul & 7] * 4u + wh];
        float w = __expf(lrelu(aW + adw));
        unsigned hw[8];
        #pragma unroll
        for (int j = 0; j < 8; j++) hw[j] = Hh[s[j] * 64u + ul];
        #pragma unroll
        for (int j = 0; j < 8; j++){
            float wj = __shfl(w, wsrc + j);
            float2 hv = h2f2(hw[j]);
            den  += wj;
            accx += wj * hv.x;
            accy += wj * hv.y;
        }
    }
    for (; i < deg; i++){
        unsigned s = (unsigned)ep[i];
        float w = __expf(lrelu(asrc[s * 4u + hd] + adh));
        float2 hv = h2f2(Hh[s * 64u + ul]);
        den  += w;
        accx += w * hv.x;
        accy += w * hv.y;
    }
    float rdh = 1.f / den;
    accx *= rdh; accy *= rdh;

    int c = lane * 2;
    if (!MEAN){
        float ox = elu_f(accx + bias[c]);
        float oy = elu_f(accy + bias[c + 1]);
        *(unsigned*)(O + (size_t)n * 128 + c) = f2h2(ox, oy);
    } else {
        float sx = accx, sy = accy;
        sx += __shfl_xor(sx, 16); sy += __shfl_xor(sy, 16);
        sx += __shfl_xor(sx, 32); sy += __shfl_xor(sy, 32);
        if (lane < 16){
            int cc = lane * 2;
            float ox = elu_f(sx * 0.25f + bias[cc]);
            float oy = elu_f(sy * 0.25f + bias[cc + 1]);
            *(float2*)(Of + (size_t)n * 32 + cc) = make_float2(ox, oy);
        }
    }
}

// ---------------- readout ----------------

__global__ void k_readout(const float* __restrict__ H3, const int* __restrict__ batch,
                          const float* __restrict__ lw, const float* __restrict__ lb,
                          float* __restrict__ pool, float* __restrict__ cnt, int n_nodes){
    __shared__ float pl[64];
    __shared__ float cl[64];
    if (threadIdx.x < 64){ pl[threadIdx.x] = 0.f; cl[threadIdx.x] = 0.f; }
    __syncthreads();
    int n = blockIdx.x * 256 + threadIdx.x;
    if (n < n_nodes){
        const float4* hp = (const float4*)(H3 + (size_t)n * 32);
        const float4* wp = (const float4*)lw;
        float y = 0.f;
        #pragma unroll
        for (int i = 0; i < 8; i++){
            float4 h4 = hp[i], w4 = wp[i];
            y += h4.x * w4.x + h4.y * w4.y + h4.z * w4.z + h4.w * w4.w;
        }
        y += lb[0];
        int b = batch[n];
        atomicAdd(&pl[b], y);
        atomicAdd(&cl[b], 1.f);
    }
    __syncthreads();
    if (threadIdx.x < 64 && cl[threadIdx.x] != 0.f){
        atomicAdd(&pool[threadIdx.x], pl[threadIdx.x]);
        atomicAdd(&cnt[threadIdx.x], cl[threadIdx.x]);
    }
}

__global__ void k_final(const float* __restrict__ pool, const float* __restrict__ cnt,
                        float* __restrict__ out){
    int g = threadIdx.x;
    if (g < 64) out[g] = (cnt[g] > 0.f) ? pool[g] / cnt[g] : 0.f;
}

// ---------------- launch ----------------

extern "C" void kernel_launch(void* const* d_in, const int* in_sizes, int n_in,
                              void* d_out, int out_size, void* d_ws, size_t ws_size,
                              hipStream_t stream){
    const float* x   = (const float*)d_in[0];
    const int*   ei  = (const int*)  d_in[1];
    const int*   bat = (const int*)  d_in[2];
    const float* W1  = (const float*)d_in[3];
    const float* a1s = (const float*)d_in[4];
    const float* a1d = (const float*)d_in[5];
    const float* b1  = (const float*)d_in[6];
    const float* W2  = (const float*)d_in[7];
    const float* a2s = (const float*)d_in[8];
    const float* a2d = (const float*)d_in[9];
    const float* b2  = (const float*)d_in[10];
    const float* W3  = (const float*)d_in[11];
    const float* a3s = (const float*)d_in[12];
    const float* a3d = (const float*)d_in[13];
    const float* b3  = (const float*)d_in[14];
    const float* lw  = (const float*)d_in[15];
    const float* lb  = (const float*)d_in[16];
    (void)n_in; (void)out_size; (void)ws_size;

    const int n_nodes = in_sizes[0] / D1;      // 100000
    const int n_edges = in_sizes[1] / 2;       // 1600000
    const int etot    = n_edges + n_nodes;     // 1700000
    const int nbin    = (n_nodes + BIN_NODES - 1) >> NODE_SHIFT;   // 196

    char* p = (char*)d_ws;
    size_t off = 0;
    auto alloc = [&](size_t bytes) -> char* {
        char* r = p + off;
        off = (off + bytes + 511) & ~(size_t)511;
        return r;
    };
    unsigned short* Hh   = (unsigned short*)alloc((size_t)n_nodes * 128 * 2); // 25.6 MB
    unsigned short* Xh   = (unsigned short*)alloc((size_t)n_nodes * 128 * 2); // 25.6 MB
    float*          asrc = (float*)alloc((size_t)n_nodes * 4 * 4);
    float*          adst = (float*)alloc((size_t)n_nodes * 4 * 4);
    unsigned short* Bp   = (unsigned short*)alloc(3 * 16384 * 2);
    int*      rowptr  = (int*)alloc((size_t)(n_nodes + 1) * 4);
    int*      eidx    = (int*)alloc((size_t)etot * 4);
    unsigned* staged  = (unsigned*)alloc((size_t)etot * 4);        // 6.8 MB packed
    int*      binCnt  = (int*)alloc(MAXBIN * 4);
    int*      binStart= (int*)alloc((MAXBIN + 1) * 4);
    int*      binCur  = (int*)alloc(MAXBIN * 4);
    float*    pool    = (float*)alloc(64 * 4);
    float*    cnt     = (float*)alloc(64 * 4);
    float*    h3      = (float*)Xh;            // alias: Xh not read by layer-3 aggr

    hipMemsetAsync(binCnt, 0, MAXBIN * 4, stream);
    hipMemsetAsync(pool, 0, 64 * 4, stream);
    hipMemsetAsync(cnt, 0, 64 * 4, stream);

    k_prepw<<<192, 256, 0, stream>>>(W1, W2, W3, Bp);

    int cb = (etot + 4095) / 4096;             // 416 chunks
    kb_hist<<<cb, 256, 0, stream>>>(ei, binCnt, n_edges, etot, nbin);
    kb_scan<<<1, 64, 0, stream>>>(binCnt, binStart, binCur, nbin, rowptr, n_nodes, etot);
    kb_scatter<<<cb, 256, 0, stream>>>(ei, binCur, staged, n_edges, etot, nbin);
    kb_final<<<nbin, 512, 0, stream>>>(staged, binStart, rowptr, eidx, n_nodes);

    int mb = (n_nodes + 127) / 128;
    int rb = (n_nodes + 3) / 4;

    // layer 1 (fp32 x -> f16 in registers)
    k_mgemm<1><<<mb, 256, 0, stream>>>(x, nullptr, Bp,
                                       a1s, a1d, Hh, asrc, adst, n_nodes);
    k_aggr<0><<<rb, 256, 0, stream>>>((const unsigned*)Hh, asrc, adst, rowptr, eidx,
                                      b1, Xh, nullptr, n_nodes);
    // layer 2
    k_mgemm<0><<<mb, 256, 0, stream>>>(nullptr, Xh, Bp + 16384,
                                       a2s, a2d, Hh, asrc, adst, n_nodes);
    k_aggr<0><<<rb, 256, 0, stream>>>((const unsigned*)Hh, asrc, adst, rowptr, eidx,
                                      b2, Xh, nullptr, n_nodes);
    // layer 3
    k_mgemm<0><<<mb, 256, 0, stream>>>(nullptr, Xh, Bp + 32768,
                                       a3s, a3d, Hh, asrc, adst, n_nodes);
    k_aggr<1><<<rb, 256, 0, stream>>>((const unsigned*)Hh, asrc, adst, rowptr, eidx,
                                      b3, nullptr, h3, n_nodes);

    int ob = (n_nodes + 255) / 256;
    k_readout<<<ob, 256, 0, stream>>>(h3, bat, lw, lb, pool, cnt, n_nodes);
    k_final<<<1, 64, 0, stream>>>(pool, cnt, (float*)d_out);
}